// Round 7
// baseline (607.588 us; speedup 1.0000x reference)
//
#include <hip/hip_runtime.h>

#define S    4096
#define DM   1024
#define H    16
#define DK   64

typedef __bf16 bf16;
typedef __bf16 bf16x8 __attribute__((ext_vector_type(8)));
typedef __bf16 bf16x4 __attribute__((ext_vector_type(4)));
typedef float  f32x4  __attribute__((ext_vector_type(4)));

// ---------------------------------------------------------------------------
// fp32 -> bf16 bulk convert: x (4M elems) + Wq/Wk/Wv/Wo (1M each) = 8M elems.
// R6 lesson: folding this cast into GEMM staging costs 2x the GEMM (adds
// bytes+VALU to the barrier-to-barrier critical path). Standalone = 12us.
// ---------------------------------------------------------------------------
__global__ __launch_bounds__(256)
void convert_kernel(const float* __restrict__ x,  const float* __restrict__ wq,
                    const float* __restrict__ wk, const float* __restrict__ wv,
                    const float* __restrict__ wo,
                    bf16* __restrict__ xb,  bf16* __restrict__ wqb,
                    bf16* __restrict__ wkb, bf16* __restrict__ wvb,
                    bf16* __restrict__ wob)
{
    const size_t i = (size_t)blockIdx.x * 256 + threadIdx.x;   // f32x4 index
    const float* src; bf16* dst; size_t off;
    if (i < 1048576)      { src = x;  dst = xb;  off = i; }
    else if (i < 1310720) { src = wq; dst = wqb; off = i - 1048576; }
    else if (i < 1572864) { src = wk; dst = wkb; off = i - 1310720; }
    else if (i < 1835008) { src = wv; dst = wvb; off = i - 1572864; }
    else                  { src = wo; dst = wob; off = i - 1835008; }
    f32x4 v = ((const f32x4*)src)[off];
    bf16x4 b;
    for (int r = 0; r < 4; r++) b[r] = (bf16)v[r];
    ((bf16x4*)dst)[off] = b;
}

// ---------------------------------------------------------------------------
// R7 GEMM: C(4096xDM) = A @ W^T, bf16 in, fp32 acc. Tile 64m x 256n, BK=64,
// 4 waves; EACH WAVE owns a 64x64 output (4x4 16x16x32 frags).
// Per wave-iter: 16 ds_read_b128, 0 ds_writes, 32 MFMA = 2.0 MFMA/LDS-op
// (R3's 64^2/2x2 was 0.67 -> its 68.6us WAS the LDS-pipe floor).
// Staging: global_load_lds width-16 into FRAGMENT-MAJOR LDS (R4/R5 main loop
// - measured 0 bank conflicts). A-panel (8 frags) shared by all waves; B
// 8 frags per wave private. LDS 40KB -> grid (64,4,3) = 3 blocks/CU.
// EPILOGUE = R3's proven per-lane store pattern VERBATIM (WRITE 26MB).
// Controlled experiment: keeps gload_lds, reverts 128^2 geometry. If the
// R4/R5 phantom 1.1GB WRITE reappears -> gload_lds is the trigger; if
// WRITE ~27MB -> 128^2 geometry was.
// mode = base_mode + blockIdx.z:
//   0: Q  -> fused RoPE, *0.125*log2(e), bf16 [h][s][d]
//   1: K  -> fused RoPE,                 bf16 [h][s][d]
//   2: V  ->                             bf16 [h][d][s] (transposed)
//   3: out ->                            fp32 [m][n] to of
// ---------------------------------------------------------------------------
__global__ __launch_bounds__(256)
void gemm_kernel(const bf16* __restrict__ A,
                 const bf16* __restrict__ w0, const bf16* __restrict__ w1,
                 const bf16* __restrict__ w2,
                 const int* __restrict__ pos,
                 bf16* __restrict__ o0, bf16* __restrict__ o1,
                 bf16* __restrict__ o2,
                 float* __restrict__ of,
                 int base_mode)
{
    const int z    = blockIdx.z;
    const int mode = base_mode + z;
    const bf16* W  = (z == 0) ? w0 : (z == 1 ? w1 : w2);
    bf16* Out      = (z == 0) ? o0 : (z == 1 ? o1 : o2);

    // fragment-major LDS: fragment = 512 bf16 (1KB), lane l holds 8 elems at
    // l*8: row = base + (l&15), k8 = (l>>4). A: frag fa=(rg<<1)|kk (8 frags).
    // B: frag fb = wv*8 + (fn<<1|kk) (32 frags).
    __shared__ bf16 As[8 * 512];       //  8 KB
    __shared__ bf16 Bs[32 * 512];      // 32 KB

    const int tid  = threadIdx.x;
    const int lane = tid & 63;
    const int wv   = tid >> 6;
    const int quad = lane >> 4;
    const int col  = lane & 15;

    const int tileM = blockIdx.x * 64;
    const int tileN = blockIdx.y * 256;

    f32x4 acc[4][4] = {};              // [fm][fn], wave's 64x64 output

    for (int kc = 0; kc < DM; kc += 64) {
        __syncthreads();               // prior-iter LDS fragment reads done
#pragma unroll
        for (int i = 0; i < 2; i++) {  // wave stages 2 of the 8 shared A frags
            const int fa = wv * 2 + i;
            const int rg = fa >> 1, kk = fa & 1;
            const size_t go = (size_t)(tileM + rg * 16 + col) * DM + kc + kk * 32 + quad * 8;
            __builtin_amdgcn_global_load_lds(
                (const __attribute__((address_space(1))) void*)(A + go),
                (__attribute__((address_space(3))) void*)&As[fa * 512], 16, 0, 0);
        }
#pragma unroll
        for (int i = 0; i < 8; i++) {  // wave stages its own 8 B frags
            const int fn = i >> 1, kk = i & 1;
            const size_t go = (size_t)(tileN + wv * 64 + fn * 16 + col) * DM + kc + kk * 32 + quad * 8;
            __builtin_amdgcn_global_load_lds(
                (const __attribute__((address_space(1))) void*)(W + go),
                (__attribute__((address_space(3))) void*)&Bs[(wv * 8 + i) * 512], 16, 0, 0);
        }
        __syncthreads();               // compiler drains vmcnt(0) before barrier

#pragma unroll
        for (int kk = 0; kk < 2; kk++) {
            bf16x8 af[4], bfr[4];
#pragma unroll
            for (int fm = 0; fm < 4; fm++)
                af[fm] = *(const bf16x8*)&As[((fm << 1) | kk) * 512 + lane * 8];
#pragma unroll
            for (int fn = 0; fn < 4; fn++)
                bfr[fn] = *(const bf16x8*)&Bs[(wv * 8 + ((fn << 1) | kk)) * 512 + lane * 8];
#pragma unroll
            for (int fm = 0; fm < 4; fm++)
#pragma unroll
                for (int fn = 0; fn < 4; fn++)
                    acc[fm][fn] = __builtin_amdgcn_mfma_f32_16x16x32_bf16(af[fm], bfr[fn], acc[fm][fn], 0, 0, 0);
        }
    }

    // Epilogue: R3's proven per-lane pattern. C/D: col = lane&15, row = quad*4+r
    for (int fm = 0; fm < 4; fm++)
    for (int fn = 0; fn < 4; fn++) {
        f32x4 v = acc[fm][fn];
        const int n = tileN + wv * 64 + fn * 16 + col;
        for (int r = 0; r < 4; r++) {
            const int m = tileM + fm * 16 + quad * 4 + r;
            float val = v[r];
            if (mode <= 1) {
                // RoPE: pairs (2i,2i+1); partner value lives in lane^1
                float part = __shfl_xor(val, 1);
                const int d = n & 63;
                const int i = d >> 1;
                float inv = exp2f(-(float)i * 0.41524101186092034f); // 1e4^(-i/32)
                float ang = (float)pos[m] * inv;
                float c = cosf(ang), sn = sinf(ang);
                float rot = (n & 1) ? (val * c + part * sn)
                                    : (val * c - part * sn);
                // Q: fold 1/sqrt(DK) AND log2(e) so attn can use raw exp2
                if (mode == 0) rot *= 0.18033688011112042f;   // 0.125*log2(e)
                Out[((size_t)(n >> 6) * S + m) * 64 + d] = (bf16)rot;
            } else if (mode == 2) {
                Out[(size_t)n * S + m] = (bf16)val;           // V^T [h][d][s]
            } else {
                of[(size_t)m * DM + n] = val;                 // out fp32
            }
        }
    }
}

// ---------------------------------------------------------------------------
// Flash attention (causal), transposed scores: St = K.Q^T, col = query.
// UNSHIFTED softmax -> partial (o,l) over disjoint key ranges sum linearly.
// R3 structure (verified): 64 queries/wave, split-K=2, antithetic pairing,
// XCD head-pinning. ~60us.
// ---------------------------------------------------------------------------
__global__ __launch_bounds__(256, 2)
void attn_kernel(const bf16* __restrict__ q, const bf16* __restrict__ k,
                 const bf16* __restrict__ vt,
                 bf16* __restrict__ P0g, bf16* __restrict__ P1g,
                 float* __restrict__ l0g, float* __restrict__ l1g)
{
    const int bid = blockIdx.x;
    const int xcd = bid & 7;
    const int b3  = (bid >> 3) & 1;
    const int u   = (bid >> 4) & 15;
    const int b8  = (bid >> 8) & 1;
    const int h   = (xcd << 1) | b8;
    const int z   = b3;
    const int QB  = (b3 == b8) ? (15 - u) : u;   // antithetic pair balance

    const int tid  = threadIdx.x;
    const int lane = tid & 63;
    const int wv   = tid >> 6;
    const int quad = lane >> 4;
    const int col  = lane & 15;

    const int T2  = 2 * QB + 2;          // tiles per split-K chunk
    const int kt0 = z * T2;
    const int kt1 = kt0 + T2;

    __shared__ bf16 Ks[64 * 72];         // K[key][d],   padded (2-way free)
    __shared__ bf16 Vs[64 * 72];         // V^T[d][key], padded
    __shared__ bf16 plds[4][64 * 40];    // per-wave P half-tile [q][32key+pad]

    const int qbase = QB * 256 + wv * 64;    // wave owns 64 queries

    // Q as B-operand fragments: B[n=q][kdim=d], 4 q-groups of 16
    bf16x8 qf[4][2];
#pragma unroll
    for (int qt = 0; qt < 4; qt++) {
        const bf16* qr = &q[((size_t)(h * S + qbase + qt * 16 + col)) * 64];
        qf[qt][0] = *(const bf16x8*)(qr + quad * 8);
        qf[qt][1] = *(const bf16x8*)(qr + 32 + quad * 8);
    }

    float li[4] = {};
    f32x4 o[4][4] = {};                  // [dg][qt]

    const int srow = tid >> 2;
    const int sseg = (tid & 3) * 16;
    const bf16* kg_ = k  + ((size_t)h * S) * 64;
    const bf16* vg_ = vt + ((size_t)h * 64) * S;

    // preload first tile of this chunk
    bf16x8 kr0 = *(const bf16x8*)(kg_ + (size_t)(kt0 * 64 + srow) * 64 + sseg);
    bf16x8 kr1 = *(const bf16x8*)(kg_ + (size_t)(kt0 * 64 + srow) * 64 + sseg + 8);
    bf16x8 vr0 = *(const bf16x8*)(vg_ + (size_t)srow * S + kt0 * 64 + sseg);
    bf16x8 vr1 = *(const bf16x8*)(vg_ + (size_t)srow * S + kt0 * 64 + sseg + 8);

    for (int kt = kt0; kt < kt1; kt++) {
        const int kbase = kt * 64;

        __syncthreads();                 // prior-iter LDS fragment reads done
        *(bf16x8*)&Ks[srow * 72 + sseg]     = kr0;
        *(bf16x8*)&Ks[srow * 72 + sseg + 8] = kr1;
        *(bf16x8*)&Vs[srow * 72 + sseg]     = vr0;
        *(bf16x8*)&Vs[srow * 72 + sseg + 8] = vr1;
        __syncthreads();

        // register-prefetch next tile (overlaps with compute below)
        if (kt + 1 < kt1) {
            const int nb = kbase + 64;
            kr0 = *(const bf16x8*)(kg_ + (size_t)(nb + srow) * 64 + sseg);
            kr1 = *(const bf16x8*)(kg_ + (size_t)(nb + srow) * 64 + sseg + 8);
            vr0 = *(const bf16x8*)(vg_ + (size_t)srow * S + nb + sseg);
            vr1 = *(const bf16x8*)(vg_ + (size_t)srow * S + nb + sseg + 8);
        }

        const bool diag = (kt >= (QB << 2));   // tile overlaps causal diagonal

        // Process 64 keys in two 32-key halves (plds holds one half)
#pragma unroll
        for (int half = 0; half < 2; half++) {
            __builtin_amdgcn_wave_barrier();   // prior half's P reads done
#pragma unroll
            for (int kg2 = 0; kg2 < 2; kg2++) {
                const int kg = half * 2 + kg2;
                // K A-fragments (shared across the 4 q-groups)
                bf16x8 kf0 = *(const bf16x8*)&Ks[(kg * 16 + col) * 72 + quad * 8];
                bf16x8 kf1 = *(const bf16x8*)&Ks[(kg * 16 + col) * 72 + 32 + quad * 8];

                f32x4 st[4];
                __builtin_amdgcn_s_setprio(1);
#pragma unroll
                for (int qt = 0; qt < 4; qt++) {
                    f32x4 zz = {};
                    zz = __builtin_amdgcn_mfma_f32_16x16x32_bf16(kf0, qf[qt][0], zz, 0, 0, 0);
                    zz = __builtin_amdgcn_mfma_f32_16x16x32_bf16(kf1, qf[qt][1], zz, 0, 0, 0);
                    st[qt] = zz;
                }
                __builtin_amdgcn_s_setprio(0);

                if (diag) {
#pragma unroll
                    for (int qt = 0; qt < 4; qt++) {
                        const int gq = qbase + qt * 16 + col;
#pragma unroll
                        for (int r = 0; r < 4; r++) {
                            const int gk = kbase + kg * 16 + quad * 4 + r;
                            st[qt][r] = (gk > gq) ? -1e30f : st[qt][r];
                        }
                    }
                }

                // p = exp2(s) raw; accumulate per-lane partial l (reduce once
                // at the end); write P half-tile (b64, packed)
#pragma unroll
                for (int qt = 0; qt < 4; qt++) {
                    bf16x4 pk;
#pragma unroll
                    for (int r = 0; r < 4; r++) {
                        float p;
                        asm("v_exp_f32 %0, %1" : "=v"(p) : "v"(st[qt][r]));
                        li[qt] += p;
                        pk[r] = (bf16)p;
                    }
                    *(bf16x4*)&plds[wv][(qt * 16 + col) * 40 + kg2 * 16 + quad * 4] = pk;
                }
            }

            __builtin_amdgcn_wave_barrier();   // P writes before P reads

            // PV for this 32-key half: O^T[d][q] += V^T[d][key] * P^T[key][q]
            bf16x8 pb[4];
#pragma unroll
            for (int qt = 0; qt < 4; qt++)
                pb[qt] = *(const bf16x8*)&plds[wv][(qt * 16 + col) * 40 + quad * 8];

            __builtin_amdgcn_s_setprio(1);
#pragma unroll
            for (int dg = 0; dg < 4; dg++) {
                bf16x8 va = *(const bf16x8*)&Vs[(dg * 16 + col) * 72 + half * 32 + quad * 8];
#pragma unroll
                for (int qt = 0; qt < 4; qt++)
                    o[dg][qt] = __builtin_amdgcn_mfma_f32_16x16x32_bf16(va, pb[qt], o[dg][qt], 0, 0, 0);
            }
            __builtin_amdgcn_s_setprio(0);
        }
    }

    // Cross-quad l reduction (keys split across quads), once per kernel
#pragma unroll
    for (int qt = 0; qt < 4; qt++) {
        li[qt] += __shfl_xor(li[qt], 16);
        li[qt] += __shfl_xor(li[qt], 32);
    }

    // Epilogue: store UNNORMALIZED partial o (bf16) + partial l (fp32).
    bf16*  Pz = z ? P1g : P0g;
    float* lz = z ? l1g : l0g;
#pragma unroll
    for (int dg = 0; dg < 4; dg++)
#pragma unroll
    for (int qt = 0; qt < 4; qt++) {
        const int gq = qbase + qt * 16 + col;
        bf16x4 ov;
#pragma unroll
        for (int r = 0; r < 4; r++) ov[r] = (bf16)o[dg][qt][r];
        *(bf16x4*)&Pz[(size_t)gq * DM + h * 64 + dg * 16 + quad * 4] = ov;
    }
    if (quad == 0) {
#pragma unroll
        for (int qt = 0; qt < 4; qt++)
            lz[(size_t)h * S + qbase + qt * 16 + col] = li[qt];
    }
}

// ---------------------------------------------------------------------------
// Combine split-K partials: ao[s][dm] = (P0 + P1) / (l0[h][s] + l1[h][s]).
// ---------------------------------------------------------------------------
__global__ __launch_bounds__(256)
void combine_kernel(const bf16* __restrict__ P0, const bf16* __restrict__ P1,
                    const float* __restrict__ l0, const float* __restrict__ l1,
                    bf16* __restrict__ ao)
{
    const size_t i    = (size_t)blockIdx.x * 256 + threadIdx.x;  // 8-elem group
    const size_t base = i * 8;
    const int s  = (int)(base >> 10);          // DM = 1024
    const int dm = (int)(base & 1023);
    const int h  = dm >> 6;
    const float rli = 1.f / (l0[(size_t)h * S + s] + l1[(size_t)h * S + s]);
    bf16x8 a = *(const bf16x8*)&P0[base];
    bf16x8 b = *(const bf16x8*)&P1[base];
    bf16x8 ov;
    for (int r = 0; r < 8; r++)
        ov[r] = (bf16)(((float)a[r] + (float)b[r]) * rli);
    *(bf16x8*)&ao[base] = ov;
}

// ---------------------------------------------------------------------------
extern "C" void kernel_launch(void* const* d_in, const int* in_sizes, int n_in,
                              void* d_out, int out_size, void* d_ws, size_t ws_size,
                              hipStream_t stream)
{
    const float* x   = (const float*)d_in[0];
    const int*   pos = (const int*)d_in[1];
    const float* Wq  = (const float*)d_in[2];
    const float* Wk  = (const float*)d_in[3];
    const float* Wv  = (const float*)d_in[4];
    const float* Wo  = (const float*)d_in[5];
    float* out = (float*)d_out;   // reference output dtype is float32

    // workspace layout (48 MB), regions recycled across phases:
    //   [0, 8M)    xb  bf16 [s][DM]        -> P0 bf16 partial (after QKV gemm)
    //   [8,16M)    wqb/wkb/wvb             -> P1 bf16 partial (after QKV gemm)
    //   [16,24M)   qb  bf16 [h][s][d]      -> ao bf16 [s][DM] (after attn)
    //   [24,32M)   kb  bf16 [h][s][d]
    //   [32,40M)   vt  bf16 [h][d][s]
    //   [40,40.25M) l0 fp32 [h][s]   [40.25,40.5M) l1 fp32 [h][s]
    //   [46,48M)   wob bf16  (must survive until gemmo -> own slot)
    char* w = (char*)d_ws;
    bf16*  xb  = (bf16*)(w);
    bf16*  wqb = (bf16*)(w + (size_t) 8 * 1024 * 1024);
    bf16*  wkb = (bf16*)(w + (size_t)10 * 1024 * 1024);
    bf16*  wvb = (bf16*)(w + (size_t)12 * 1024 * 1024);
    bf16*  P0  = (bf16*)(w);
    bf16*  P1  = (bf16*)(w + (size_t) 8 * 1024 * 1024);
    bf16*  qb  = (bf16*)(w + (size_t)16 * 1024 * 1024);
    bf16*  kb  = (bf16*)(w + (size_t)24 * 1024 * 1024);
    bf16*  vt  = (bf16*)(w + (size_t)32 * 1024 * 1024);
    float* l0  = (float*)(w + (size_t)40 * 1024 * 1024);
    float* l1  = (float*)(w + (size_t)40 * 1024 * 1024 + 256 * 1024);
    bf16*  ao  = (bf16*)(w + (size_t)16 * 1024 * 1024);   // alias qb (dead)
    bf16*  wob = (bf16*)(w + (size_t)46 * 1024 * 1024);

    dim3 blk(256);
    convert_kernel<<<dim3(8192), blk, 0, stream>>>(x, Wq, Wk, Wv, Wo,
                                                   xb, wqb, wkb, wvb, wob);
    gemm_kernel<<<dim3(64, 4, 3), blk, 0, stream>>>(xb, wqb, wkb, wvb, pos,
                                                    qb, kb, vt, out, 0);
    attn_kernel<<<dim3(512), blk, 0, stream>>>(qb, kb, vt,
                                               P0, P1, l0, l1);
    combine_kernel<<<dim3(2048), blk, 0, stream>>>(P0, P1, l0, l1, ao);
    gemm_kernel<<<dim3(64, 4, 1), blk, 0, stream>>>(ao, wob, wob, wob, pos,
                                                    qb, kb, vt, out, 3);
}

// Round 9
// 570.689 us; speedup vs baseline: 1.0647x; 1.0647x over previous
//
#include <hip/hip_runtime.h>

#define S    4096
#define DM   1024
#define H    16
#define DK   64

typedef __bf16 bf16;
typedef __bf16 bf16x8 __attribute__((ext_vector_type(8)));
typedef __bf16 bf16x4 __attribute__((ext_vector_type(4)));
typedef float  f32x4  __attribute__((ext_vector_type(4)));

// ---------------------------------------------------------------------------
// fp32 -> bf16 bulk convert: x (4M elems) + Wq/Wk/Wv/Wo (1M each) = 8M elems.
// R6 lesson: folding this cast into GEMM staging costs 2x the GEMM. 12us.
// ---------------------------------------------------------------------------
__global__ __launch_bounds__(256)
void convert_kernel(const float* __restrict__ x,  const float* __restrict__ wq,
                    const float* __restrict__ wk, const float* __restrict__ wv,
                    const float* __restrict__ wo,
                    bf16* __restrict__ xb,  bf16* __restrict__ wqb,
                    bf16* __restrict__ wkb, bf16* __restrict__ wvb,
                    bf16* __restrict__ wob)
{
    const size_t i = (size_t)blockIdx.x * 256 + threadIdx.x;   // f32x4 index
    const float* src; bf16* dst; size_t off;
    if (i < 1048576)      { src = x;  dst = xb;  off = i; }
    else if (i < 1310720) { src = wq; dst = wqb; off = i - 1048576; }
    else if (i < 1572864) { src = wk; dst = wkb; off = i - 1310720; }
    else if (i < 1835008) { src = wv; dst = wvb; off = i - 1572864; }
    else                  { src = wo; dst = wob; off = i - 1835008; }
    f32x4 v = ((const f32x4*)src)[off];
    bf16x4 b;
    for (int r = 0; r < 4; r++) b[r] = (bf16)v[r];
    ((bf16x4*)dst)[off] = b;
}

// ---------------------------------------------------------------------------
// R9 GEMM: C(4096xDM) = A @ W^T, bf16 in, fp32 acc. Tile 64m x 256n, BK=64,
// 4 waves side-by-side; EACH WAVE owns a 64x64 output (4x4 16x16x32 frags).
// Built ONLY from R3-proven elements:
//  - staging mechanism: load current tile -> sync -> ds_write -> sync ->
//    compute (NO cross-iter reg prefetch [R8 raced], NO global_load_lds
//    [R4/R5/R7: phantom 1.1GB WRITE_SIZE]);
//  - staging addressing: ldRow=tid>>2, ldK=(tid&3)*16, b128 at row*72+ldK
//    (4 consecutive lanes = 128B contiguous global; LDS stride 72);
//  - LDS read pattern: (g*16+col)*72 + kk*32 + quad*8 (2-way aliasing, free);
//  - epilogue: R3 verbatim (WRITE_SIZE 26MB proven).
// Gain vs R3: 26 LDS-ops per 32 MFMA (1.23) vs 12 per 8 (0.67) -> 1.85x
// better LDS-pipe ratio; floor ~25us/CU + MFMA 12.8us.
// LDS 45KB -> 3 blocks/CU; grid (64,4,z) = 768 blocks = 3/CU exact.
// mode = base_mode + blockIdx.z:
//   0: Q  -> fused RoPE, *0.125*log2(e), bf16 [h][s][d]
//   1: K  -> fused RoPE,                 bf16 [h][s][d]
//   2: V  ->                             bf16 [h][d][s] (transposed)
//   3: out ->                            fp32 [m][n] to of
// ---------------------------------------------------------------------------
__global__ __launch_bounds__(256)
void gemm_kernel(const bf16* __restrict__ A,
                 const bf16* __restrict__ w0, const bf16* __restrict__ w1,
                 const bf16* __restrict__ w2,
                 const int* __restrict__ pos,
                 bf16* __restrict__ o0, bf16* __restrict__ o1,
                 bf16* __restrict__ o2,
                 float* __restrict__ of,
                 int base_mode)
{
    const int z    = blockIdx.z;
    const int mode = base_mode + z;
    const bf16* W  = (z == 0) ? w0 : (z == 1 ? w1 : w2);
    bf16* Out      = (z == 0) ? o0 : (z == 1 ? o1 : o2);

    __shared__ bf16 As[64 * 72];        //  9 KB
    __shared__ bf16 Bs[256 * 72];       // 36 KB

    const int tid  = threadIdx.x;
    const int lane = tid & 63;
    const int wv   = tid >> 6;
    const int quad = lane >> 4;
    const int col  = lane & 15;

    const int tileM = blockIdx.x * 64;
    const int tileN = blockIdx.y * 256;

    const int ldRow = tid >> 2;         // 0..63
    const int ldK   = (tid & 3) * 16;   // 0,16,32,48 (elements)

    f32x4 acc[4][4] = {};               // [fm][fn], wave's 64x64 output

    for (int kc = 0; kc < DM; kc += 64) {
        // load current K-tile: A 64 rows, B 256 rows (4 row-blocks of 64)
        bf16x8 a0 = *(const bf16x8*)&A[(size_t)(tileM + ldRow) * DM + kc + ldK];
        bf16x8 a1 = *(const bf16x8*)&A[(size_t)(tileM + ldRow) * DM + kc + ldK + 8];
        bf16x8 b[4][2];
#pragma unroll
        for (int rb = 0; rb < 4; rb++) {
            const bf16* bp = &W[(size_t)(tileN + rb * 64 + ldRow) * DM + kc + ldK];
            b[rb][0] = *(const bf16x8*)(bp);
            b[rb][1] = *(const bf16x8*)(bp + 8);
        }
        __syncthreads();                       // prior-iter LDS reads done
        *(bf16x8*)&As[ldRow * 72 + ldK]     = a0;
        *(bf16x8*)&As[ldRow * 72 + ldK + 8] = a1;
#pragma unroll
        for (int rb = 0; rb < 4; rb++) {
            *(bf16x8*)&Bs[(rb * 64 + ldRow) * 72 + ldK]     = b[rb][0];
            *(bf16x8*)&Bs[(rb * 64 + ldRow) * 72 + ldK + 8] = b[rb][1];
        }
        __syncthreads();

#pragma unroll
        for (int kk = 0; kk < 2; kk++) {
            bf16x8 af[4], bfr[4];
#pragma unroll
            for (int fm = 0; fm < 4; fm++)
                af[fm] = *(const bf16x8*)&As[(fm * 16 + col) * 72 + kk * 32 + quad * 8];
#pragma unroll
            for (int fn = 0; fn < 4; fn++)
                bfr[fn] = *(const bf16x8*)&Bs[(wv * 64 + fn * 16 + col) * 72 + kk * 32 + quad * 8];
#pragma unroll
            for (int fm = 0; fm < 4; fm++)
#pragma unroll
                for (int fn = 0; fn < 4; fn++)
                    acc[fm][fn] = __builtin_amdgcn_mfma_f32_16x16x32_bf16(af[fm], bfr[fn], acc[fm][fn], 0, 0, 0);
        }
    }

    // Epilogue: R3's proven per-lane pattern. C/D: col = lane&15, row = quad*4+r
    for (int fm = 0; fm < 4; fm++)
    for (int fn = 0; fn < 4; fn++) {
        f32x4 v = acc[fm][fn];
        const int n = tileN + wv * 64 + fn * 16 + col;
        for (int r = 0; r < 4; r++) {
            const int m = tileM + fm * 16 + quad * 4 + r;
            float val = v[r];
            if (mode <= 1) {
                // RoPE: pairs (2i,2i+1); partner value lives in lane^1
                float part = __shfl_xor(val, 1);
                const int d = n & 63;
                const int i = d >> 1;
                float inv = exp2f(-(float)i * 0.41524101186092034f); // 1e4^(-i/32)
                float ang = (float)pos[m] * inv;
                float c = cosf(ang), sn = sinf(ang);
                float rot = (n & 1) ? (val * c + part * sn)
                                    : (val * c - part * sn);
                // Q: fold 1/sqrt(DK) AND log2(e) so attn can use raw exp2
                if (mode == 0) rot *= 0.18033688011112042f;   // 0.125*log2(e)
                Out[((size_t)(n >> 6) * S + m) * 64 + d] = (bf16)rot;
            } else if (mode == 2) {
                Out[(size_t)n * S + m] = (bf16)val;           // V^T [h][d][s]
            } else {
                of[(size_t)m * DM + n] = val;                 // out fp32
            }
        }
    }
}

// ---------------------------------------------------------------------------
// Flash attention (causal), transposed scores: St = K.Q^T, col = query.
// UNSHIFTED softmax -> partial (o,l) over disjoint key ranges sum linearly.
// R3 structure (verified): 64 queries/wave, split-K=2, antithetic pairing,
// XCD head-pinning. ~60us.
// ---------------------------------------------------------------------------
__global__ __launch_bounds__(256, 2)
void attn_kernel(const bf16* __restrict__ q, const bf16* __restrict__ k,
                 const bf16* __restrict__ vt,
                 bf16* __restrict__ P0g, bf16* __restrict__ P1g,
                 float* __restrict__ l0g, float* __restrict__ l1g)
{
    const int bid = blockIdx.x;
    const int xcd = bid & 7;
    const int b3  = (bid >> 3) & 1;
    const int u   = (bid >> 4) & 15;
    const int b8  = (bid >> 8) & 1;
    const int h   = (xcd << 1) | b8;
    const int z   = b3;
    const int QB  = (b3 == b8) ? (15 - u) : u;   // antithetic pair balance

    const int tid  = threadIdx.x;
    const int lane = tid & 63;
    const int wv   = tid >> 6;
    const int quad = lane >> 4;
    const int col  = lane & 15;

    const int T2  = 2 * QB + 2;          // tiles per split-K chunk
    const int kt0 = z * T2;
    const int kt1 = kt0 + T2;

    __shared__ bf16 Ks[64 * 72];         // K[key][d],   padded (2-way free)
    __shared__ bf16 Vs[64 * 72];         // V^T[d][key], padded
    __shared__ bf16 plds[4][64 * 40];    // per-wave P half-tile [q][32key+pad]

    const int qbase = QB * 256 + wv * 64;    // wave owns 64 queries

    // Q as B-operand fragments: B[n=q][kdim=d], 4 q-groups of 16
    bf16x8 qf[4][2];
#pragma unroll
    for (int qt = 0; qt < 4; qt++) {
        const bf16* qr = &q[((size_t)(h * S + qbase + qt * 16 + col)) * 64];
        qf[qt][0] = *(const bf16x8*)(qr + quad * 8);
        qf[qt][1] = *(const bf16x8*)(qr + 32 + quad * 8);
    }

    float li[4] = {};
    f32x4 o[4][4] = {};                  // [dg][qt]

    const int srow = tid >> 2;
    const int sseg = (tid & 3) * 16;
    const bf16* kg_ = k  + ((size_t)h * S) * 64;
    const bf16* vg_ = vt + ((size_t)h * 64) * S;

    // preload first tile of this chunk
    bf16x8 kr0 = *(const bf16x8*)(kg_ + (size_t)(kt0 * 64 + srow) * 64 + sseg);
    bf16x8 kr1 = *(const bf16x8*)(kg_ + (size_t)(kt0 * 64 + srow) * 64 + sseg + 8);
    bf16x8 vr0 = *(const bf16x8*)(vg_ + (size_t)srow * S + kt0 * 64 + sseg);
    bf16x8 vr1 = *(const bf16x8*)(vg_ + (size_t)srow * S + kt0 * 64 + sseg + 8);

    for (int kt = kt0; kt < kt1; kt++) {
        const int kbase = kt * 64;

        __syncthreads();                 // prior-iter LDS fragment reads done
        *(bf16x8*)&Ks[srow * 72 + sseg]     = kr0;
        *(bf16x8*)&Ks[srow * 72 + sseg + 8] = kr1;
        *(bf16x8*)&Vs[srow * 72 + sseg]     = vr0;
        *(bf16x8*)&Vs[srow * 72 + sseg + 8] = vr1;
        __syncthreads();

        // register-prefetch next tile (overlaps with compute below)
        if (kt + 1 < kt1) {
            const int nb = kbase + 64;
            kr0 = *(const bf16x8*)(kg_ + (size_t)(nb + srow) * 64 + sseg);
            kr1 = *(const bf16x8*)(kg_ + (size_t)(nb + srow) * 64 + sseg + 8);
            vr0 = *(const bf16x8*)(vg_ + (size_t)srow * S + nb + sseg);
            vr1 = *(const bf16x8*)(vg_ + (size_t)srow * S + nb + sseg + 8);
        }

        const bool diag = (kt >= (QB << 2));   // tile overlaps causal diagonal

        // Process 64 keys in two 32-key halves (plds holds one half)
#pragma unroll
        for (int half = 0; half < 2; half++) {
            __builtin_amdgcn_wave_barrier();   // prior half's P reads done
#pragma unroll
            for (int kg2 = 0; kg2 < 2; kg2++) {
                const int kg = half * 2 + kg2;
                // K A-fragments (shared across the 4 q-groups)
                bf16x8 kf0 = *(const bf16x8*)&Ks[(kg * 16 + col) * 72 + quad * 8];
                bf16x8 kf1 = *(const bf16x8*)&Ks[(kg * 16 + col) * 72 + 32 + quad * 8];

                f32x4 st[4];
                __builtin_amdgcn_s_setprio(1);
#pragma unroll
                for (int qt = 0; qt < 4; qt++) {
                    f32x4 zz = {};
                    zz = __builtin_amdgcn_mfma_f32_16x16x32_bf16(kf0, qf[qt][0], zz, 0, 0, 0);
                    zz = __builtin_amdgcn_mfma_f32_16x16x32_bf16(kf1, qf[qt][1], zz, 0, 0, 0);
                    st[qt] = zz;
                }
                __builtin_amdgcn_s_setprio(0);

                if (diag) {
#pragma unroll
                    for (int qt = 0; qt < 4; qt++) {
                        const int gq = qbase + qt * 16 + col;
#pragma unroll
                        for (int r = 0; r < 4; r++) {
                            const int gk = kbase + kg * 16 + quad * 4 + r;
                            st[qt][r] = (gk > gq) ? -1e30f : st[qt][r];
                        }
                    }
                }

                // p = exp2(s) raw; accumulate per-lane partial l (reduce once
                // at the end); write P half-tile (b64, packed)
#pragma unroll
                for (int qt = 0; qt < 4; qt++) {
                    bf16x4 pk;
#pragma unroll
                    for (int r = 0; r < 4; r++) {
                        float p;
                        asm("v_exp_f32 %0, %1" : "=v"(p) : "v"(st[qt][r]));
                        li[qt] += p;
                        pk[r] = (bf16)p;
                    }
                    *(bf16x4*)&plds[wv][(qt * 16 + col) * 40 + kg2 * 16 + quad * 4] = pk;
                }
            }

            __builtin_amdgcn_wave_barrier();   // P writes before P reads

            // PV for this 32-key half: O^T[d][q] += V^T[d][key] * P^T[key][q]
            bf16x8 pb[4];
#pragma unroll
            for (int qt = 0; qt < 4; qt++)
                pb[qt] = *(const bf16x8*)&plds[wv][(qt * 16 + col) * 40 + quad * 8];

            __builtin_amdgcn_s_setprio(1);
#pragma unroll
            for (int dg = 0; dg < 4; dg++) {
                bf16x8 va = *(const bf16x8*)&Vs[(dg * 16 + col) * 72 + half * 32 + quad * 8];
#pragma unroll
                for (int qt = 0; qt < 4; qt++)
                    o[dg][qt] = __builtin_amdgcn_mfma_f32_16x16x32_bf16(va, pb[qt], o[dg][qt], 0, 0, 0);
            }
            __builtin_amdgcn_s_setprio(0);
        }
    }

    // Cross-quad l reduction (keys split across quads), once per kernel
#pragma unroll
    for (int qt = 0; qt < 4; qt++) {
        li[qt] += __shfl_xor(li[qt], 16);
        li[qt] += __shfl_xor(li[qt], 32);
    }

    // Epilogue: store UNNORMALIZED partial o (bf16) + partial l (fp32).
    bf16*  Pz = z ? P1g : P0g;
    float* lz = z ? l1g : l0g;
#pragma unroll
    for (int dg = 0; dg < 4; dg++)
#pragma unroll
    for (int qt = 0; qt < 4; qt++) {
        const int gq = qbase + qt * 16 + col;
        bf16x4 ov;
#pragma unroll
        for (int r = 0; r < 4; r++) ov[r] = (bf16)o[dg][qt][r];
        *(bf16x4*)&Pz[(size_t)gq * DM + h * 64 + dg * 16 + quad * 4] = ov;
    }
    if (quad == 0) {
#pragma unroll
        for (int qt = 0; qt < 4; qt++)
            lz[(size_t)h * S + qbase + qt * 16 + col] = li[qt];
    }
}

// ---------------------------------------------------------------------------
// Combine split-K partials: ao[s][dm] = (P0 + P1) / (l0[h][s] + l1[h][s]).
// ---------------------------------------------------------------------------
__global__ __launch_bounds__(256)
void combine_kernel(const bf16* __restrict__ P0, const bf16* __restrict__ P1,
                    const float* __restrict__ l0, const float* __restrict__ l1,
                    bf16* __restrict__ ao)
{
    const size_t i    = (size_t)blockIdx.x * 256 + threadIdx.x;  // 8-elem group
    const size_t base = i * 8;
    const int s  = (int)(base >> 10);          // DM = 1024
    const int dm = (int)(base & 1023);
    const int h  = dm >> 6;
    const float rli = 1.f / (l0[(size_t)h * S + s] + l1[(size_t)h * S + s]);
    bf16x8 a = *(const bf16x8*)&P0[base];
    bf16x8 b = *(const bf16x8*)&P1[base];
    bf16x8 ov;
    for (int r = 0; r < 8; r++)
        ov[r] = (bf16)(((float)a[r] + (float)b[r]) * rli);
    *(bf16x8*)&ao[base] = ov;
}

// ---------------------------------------------------------------------------
extern "C" void kernel_launch(void* const* d_in, const int* in_sizes, int n_in,
                              void* d_out, int out_size, void* d_ws, size_t ws_size,
                              hipStream_t stream)
{
    const float* x   = (const float*)d_in[0];
    const int*   pos = (const int*)d_in[1];
    const float* Wq  = (const float*)d_in[2];
    const float* Wk  = (const float*)d_in[3];
    const float* Wv  = (const float*)d_in[4];
    const float* Wo  = (const float*)d_in[5];
    float* out = (float*)d_out;   // reference output dtype is float32

    // workspace layout (48 MB), regions recycled across phases:
    //   [0, 8M)    xb  bf16 [s][DM]        -> P0 bf16 partial (after QKV gemm)
    //   [8,16M)    wqb/wkb/wvb             -> P1 bf16 partial (after QKV gemm)
    //   [16,24M)   qb  bf16 [h][s][d]      -> ao bf16 [s][DM] (after attn)
    //   [24,32M)   kb  bf16 [h][s][d]
    //   [32,40M)   vt  bf16 [h][d][s]
    //   [40,40.25M) l0 fp32 [h][s]   [40.25,40.5M) l1 fp32 [h][s]
    //   [46,48M)   wob bf16  (must survive until out-proj -> own slot)
    char* w = (char*)d_ws;
    bf16*  xb  = (bf16*)(w);
    bf16*  wqb = (bf16*)(w + (size_t) 8 * 1024 * 1024);
    bf16*  wkb = (bf16*)(w + (size_t)10 * 1024 * 1024);
    bf16*  wvb = (bf16*)(w + (size_t)12 * 1024 * 1024);
    bf16*  P0  = (bf16*)(w);
    bf16*  P1  = (bf16*)(w + (size_t) 8 * 1024 * 1024);
    bf16*  qb  = (bf16*)(w + (size_t)16 * 1024 * 1024);
    bf16*  kb  = (bf16*)(w + (size_t)24 * 1024 * 1024);
    bf16*  vt  = (bf16*)(w + (size_t)32 * 1024 * 1024);
    float* l0  = (float*)(w + (size_t)40 * 1024 * 1024);
    float* l1  = (float*)(w + (size_t)40 * 1024 * 1024 + 256 * 1024);
    bf16*  ao  = (bf16*)(w + (size_t)16 * 1024 * 1024);   // alias qb (dead)
    bf16*  wob = (bf16*)(w + (size_t)46 * 1024 * 1024);

    dim3 blk(256);
    convert_kernel<<<dim3(8192), blk, 0, stream>>>(x, Wq, Wk, Wv, Wo,
                                                   xb, wqb, wkb, wvb, wob);
    gemm_kernel<<<dim3(64, 4, 3), blk, 0, stream>>>(xb, wqb, wkb, wvb, pos,
                                                    qb, kb, vt, out, 0);
    attn_kernel<<<dim3(512), blk, 0, stream>>>(qb, kb, vt,
                                               P0, P1, l0, l1);
    combine_kernel<<<dim3(2048), blk, 0, stream>>>(P0, P1, l0, l1, ao);
    gemm_kernel<<<dim3(64, 4, 1), blk, 0, stream>>>(ao, wob, wob, wob, pos,
                                                    qb, kb, vt, out, 3);
}

// Round 10
// 553.836 us; speedup vs baseline: 1.0971x; 1.0304x over previous
//
#include <hip/hip_runtime.h>

#define S    4096
#define DM   1024
#define H    16
#define DK   64

typedef __bf16 bf16;
typedef __bf16 bf16x8 __attribute__((ext_vector_type(8)));
typedef __bf16 bf16x4 __attribute__((ext_vector_type(4)));
typedef float  f32x4  __attribute__((ext_vector_type(4)));

// ---------------------------------------------------------------------------
// fp32 -> bf16 bulk convert. R6 lesson: do NOT fold into GEMM staging. 12us.
// ---------------------------------------------------------------------------
__global__ __launch_bounds__(256)
void convert_kernel(const float* __restrict__ x,  const float* __restrict__ wq,
                    const float* __restrict__ wk, const float* __restrict__ wv,
                    const float* __restrict__ wo,
                    bf16* __restrict__ xb,  bf16* __restrict__ wqb,
                    bf16* __restrict__ wkb, bf16* __restrict__ wvb,
                    bf16* __restrict__ wob)
{
    const size_t i = (size_t)blockIdx.x * 256 + threadIdx.x;   // f32x4 index
    const float* src; bf16* dst; size_t off;
    if (i < 1048576)      { src = x;  dst = xb;  off = i; }
    else if (i < 1310720) { src = wq; dst = wqb; off = i - 1048576; }
    else if (i < 1572864) { src = wk; dst = wkb; off = i - 1310720; }
    else if (i < 1835008) { src = wv; dst = wvb; off = i - 1572864; }
    else                  { src = wo; dst = wob; off = i - 1835008; }
    f32x4 v = ((const f32x4*)src)[off];
    bf16x4 b;
    for (int r = 0; r < 4; r++) b[r] = (bf16)v[r];
    ((bf16x4*)dst)[off] = b;
}

// ---------------------------------------------------------------------------
// R10 GEMM: C(4096xDM) = A @ W^T. Tile 128m x 64n, BK=64, 4 waves stacked
// along m; EACH WAVE owns 32m x 64n = acc[2][4] = 32 regs.
// WRITE-STORM LAW (6 experiments): wave-acc 4x4 (64 regs) -> compiler caps
// VGPRs (~68) and spills; spill stores dirty L2 -> 1.1+ GB HBM writebacks
// (R4/R5/R7/R9, epilogue-independent). acc 2x2 (16) -> 26 MB (R3/R6).
// This kernel tests/exploits the midpoint acc 2x4 (32 regs): register
// profile close to R3's proven one, LDS ratio 1.7x better (18 LDS-instr
// per 16 MFMA vs R3's 12 per 8).
// Staging/order = R3 verbatim (load -> sync -> ds_write -> sync -> compute;
// no cross-iter reg prefetch [R8 raced], no global_load_lds). Stride-72 LDS.
// Epilogue = R3 verbatim. LDS 27.6 KB; grid (32,16,z), uniform blocks.
// mode = base_mode + blockIdx.z:
//   0: Q  -> fused RoPE, *0.125*log2(e), bf16 [h][s][d]
//   1: K  -> fused RoPE,                 bf16 [h][s][d]
//   2: V  ->                             bf16 [h][d][s] (transposed)
//   3: out ->                            fp32 [m][n] to of
// ---------------------------------------------------------------------------
__global__ __launch_bounds__(256)
void gemm_kernel(const bf16* __restrict__ A,
                 const bf16* __restrict__ w0, const bf16* __restrict__ w1,
                 const bf16* __restrict__ w2,
                 const int* __restrict__ pos,
                 bf16* __restrict__ o0, bf16* __restrict__ o1,
                 bf16* __restrict__ o2,
                 float* __restrict__ of,
                 int base_mode)
{
    const int z    = blockIdx.z;
    const int mode = base_mode + z;
    const bf16* W  = (z == 0) ? w0 : (z == 1 ? w1 : w2);
    bf16* Out      = (z == 0) ? o0 : (z == 1 ? o1 : o2);

    __shared__ bf16 As[128 * 72];       // 18 KB
    __shared__ bf16 Bs[64 * 72];        //  9 KB

    const int tid  = threadIdx.x;
    const int lane = tid & 63;
    const int wv   = tid >> 6;
    const int quad = lane >> 4;
    const int col  = lane & 15;

    const int tileM = blockIdx.x * 128;
    const int tileN = blockIdx.y * 64;

    const int ldRow = tid >> 2;         // 0..63
    const int ldK   = (tid & 3) * 16;   // 0,16,32,48 (elements)

    f32x4 acc[2][4] = {};               // [fm][fn], wave's 32x64 output

    for (int kc = 0; kc < DM; kc += 64) {
        // load current K-tile: A 128 rows (2 row-blocks), B 64 rows
        bf16x8 a[2][2];
#pragma unroll
        for (int rb = 0; rb < 2; rb++) {
            const bf16* ap = &A[(size_t)(tileM + rb * 64 + ldRow) * DM + kc + ldK];
            a[rb][0] = *(const bf16x8*)(ap);
            a[rb][1] = *(const bf16x8*)(ap + 8);
        }
        bf16x8 b0 = *(const bf16x8*)&W[(size_t)(tileN + ldRow) * DM + kc + ldK];
        bf16x8 b1 = *(const bf16x8*)&W[(size_t)(tileN + ldRow) * DM + kc + ldK + 8];
        __syncthreads();                       // prior-iter LDS reads done
#pragma unroll
        for (int rb = 0; rb < 2; rb++) {
            *(bf16x8*)&As[(rb * 64 + ldRow) * 72 + ldK]     = a[rb][0];
            *(bf16x8*)&As[(rb * 64 + ldRow) * 72 + ldK + 8] = a[rb][1];
        }
        *(bf16x8*)&Bs[ldRow * 72 + ldK]     = b0;
        *(bf16x8*)&Bs[ldRow * 72 + ldK + 8] = b1;
        __syncthreads();

#pragma unroll
        for (int kk = 0; kk < 2; kk++) {
            bf16x8 af[2], bfr[4];
#pragma unroll
            for (int fm = 0; fm < 2; fm++)
                af[fm] = *(const bf16x8*)&As[(wv * 32 + fm * 16 + col) * 72 + kk * 32 + quad * 8];
#pragma unroll
            for (int fn = 0; fn < 4; fn++)
                bfr[fn] = *(const bf16x8*)&Bs[(fn * 16 + col) * 72 + kk * 32 + quad * 8];
#pragma unroll
            for (int fm = 0; fm < 2; fm++)
#pragma unroll
                for (int fn = 0; fn < 4; fn++)
                    acc[fm][fn] = __builtin_amdgcn_mfma_f32_16x16x32_bf16(af[fm], bfr[fn], acc[fm][fn], 0, 0, 0);
        }
    }

    // Epilogue: R3's proven per-lane pattern. C/D: col = lane&15, row = quad*4+r
    for (int fm = 0; fm < 2; fm++)
    for (int fn = 0; fn < 4; fn++) {
        f32x4 v = acc[fm][fn];
        const int n = tileN + fn * 16 + col;
        for (int r = 0; r < 4; r++) {
            const int m = tileM + wv * 32 + fm * 16 + quad * 4 + r;
            float val = v[r];
            if (mode <= 1) {
                // RoPE: pairs (2i,2i+1); partner value lives in lane^1
                float part = __shfl_xor(val, 1);
                const int d = n & 63;
                const int i = d >> 1;
                float inv = exp2f(-(float)i * 0.41524101186092034f); // 1e4^(-i/32)
                float ang = (float)pos[m] * inv;
                float c = cosf(ang), sn = sinf(ang);
                float rot = (n & 1) ? (val * c + part * sn)
                                    : (val * c - part * sn);
                // Q: fold 1/sqrt(DK) AND log2(e) so attn can use raw exp2
                if (mode == 0) rot *= 0.18033688011112042f;   // 0.125*log2(e)
                Out[((size_t)(n >> 6) * S + m) * 64 + d] = (bf16)rot;
            } else if (mode == 2) {
                Out[(size_t)n * S + m] = (bf16)val;           // V^T [h][d][s]
            } else {
                of[(size_t)m * DM + n] = val;                 // out fp32
            }
        }
    }
}

// ---------------------------------------------------------------------------
// Flash attention (causal), transposed scores: St = K.Q^T, col = query.
// UNSHIFTED softmax -> partial (o,l) over disjoint key ranges sum linearly.
// R3 structure (verified): 64 queries/wave, split-K=2, antithetic pairing,
// XCD head-pinning. ~60us.
// ---------------------------------------------------------------------------
__global__ __launch_bounds__(256, 2)
void attn_kernel(const bf16* __restrict__ q, const bf16* __restrict__ k,
                 const bf16* __restrict__ vt,
                 bf16* __restrict__ P0g, bf16* __restrict__ P1g,
                 float* __restrict__ l0g, float* __restrict__ l1g)
{
    const int bid = blockIdx.x;
    const int xcd = bid & 7;
    const int b3  = (bid >> 3) & 1;
    const int u   = (bid >> 4) & 15;
    const int b8  = (bid >> 8) & 1;
    const int h   = (xcd << 1) | b8;
    const int z   = b3;
    const int QB  = (b3 == b8) ? (15 - u) : u;   // antithetic pair balance

    const int tid  = threadIdx.x;
    const int lane = tid & 63;
    const int wv   = tid >> 6;
    const int quad = lane >> 4;
    const int col  = lane & 15;

    const int T2  = 2 * QB + 2;          // tiles per split-K chunk
    const int kt0 = z * T2;
    const int kt1 = kt0 + T2;

    __shared__ bf16 Ks[64 * 72];         // K[key][d],   padded (2-way free)
    __shared__ bf16 Vs[64 * 72];         // V^T[d][key], padded
    __shared__ bf16 plds[4][64 * 40];    // per-wave P half-tile [q][32key+pad]

    const int qbase = QB * 256 + wv * 64;    // wave owns 64 queries

    // Q as B-operand fragments: B[n=q][kdim=d], 4 q-groups of 16
    bf16x8 qf[4][2];
#pragma unroll
    for (int qt = 0; qt < 4; qt++) {
        const bf16* qr = &q[((size_t)(h * S + qbase + qt * 16 + col)) * 64];
        qf[qt][0] = *(const bf16x8*)(qr + quad * 8);
        qf[qt][1] = *(const bf16x8*)(qr + 32 + quad * 8);
    }

    float li[4] = {};
    f32x4 o[4][4] = {};                  // [dg][qt]

    const int srow = tid >> 2;
    const int sseg = (tid & 3) * 16;
    const bf16* kg_ = k  + ((size_t)h * S) * 64;
    const bf16* vg_ = vt + ((size_t)h * 64) * S;

    // preload first tile of this chunk
    bf16x8 kr0 = *(const bf16x8*)(kg_ + (size_t)(kt0 * 64 + srow) * 64 + sseg);
    bf16x8 kr1 = *(const bf16x8*)(kg_ + (size_t)(kt0 * 64 + srow) * 64 + sseg + 8);
    bf16x8 vr0 = *(const bf16x8*)(vg_ + (size_t)srow * S + kt0 * 64 + sseg);
    bf16x8 vr1 = *(const bf16x8*)(vg_ + (size_t)srow * S + kt0 * 64 + sseg + 8);

    for (int kt = kt0; kt < kt1; kt++) {
        const int kbase = kt * 64;

        __syncthreads();                 // prior-iter LDS fragment reads done
        *(bf16x8*)&Ks[srow * 72 + sseg]     = kr0;
        *(bf16x8*)&Ks[srow * 72 + sseg + 8] = kr1;
        *(bf16x8*)&Vs[srow * 72 + sseg]     = vr0;
        *(bf16x8*)&Vs[srow * 72 + sseg + 8] = vr1;
        __syncthreads();

        // register-prefetch next tile (overlaps with compute below)
        if (kt + 1 < kt1) {
            const int nb = kbase + 64;
            kr0 = *(const bf16x8*)(kg_ + (size_t)(nb + srow) * 64 + sseg);
            kr1 = *(const bf16x8*)(kg_ + (size_t)(nb + srow) * 64 + sseg + 8);
            vr0 = *(const bf16x8*)(vg_ + (size_t)srow * S + nb + sseg);
            vr1 = *(const bf16x8*)(vg_ + (size_t)srow * S + nb + sseg + 8);
        }

        const bool diag = (kt >= (QB << 2));   // tile overlaps causal diagonal

        // Process 64 keys in two 32-key halves (plds holds one half)
#pragma unroll
        for (int half = 0; half < 2; half++) {
            __builtin_amdgcn_wave_barrier();   // prior half's P reads done
#pragma unroll
            for (int kg2 = 0; kg2 < 2; kg2++) {
                const int kg = half * 2 + kg2;
                // K A-fragments (shared across the 4 q-groups)
                bf16x8 kf0 = *(const bf16x8*)&Ks[(kg * 16 + col) * 72 + quad * 8];
                bf16x8 kf1 = *(const bf16x8*)&Ks[(kg * 16 + col) * 72 + 32 + quad * 8];

                f32x4 st[4];
                __builtin_amdgcn_s_setprio(1);
#pragma unroll
                for (int qt = 0; qt < 4; qt++) {
                    f32x4 zz = {};
                    zz = __builtin_amdgcn_mfma_f32_16x16x32_bf16(kf0, qf[qt][0], zz, 0, 0, 0);
                    zz = __builtin_amdgcn_mfma_f32_16x16x32_bf16(kf1, qf[qt][1], zz, 0, 0, 0);
                    st[qt] = zz;
                }
                __builtin_amdgcn_s_setprio(0);

                if (diag) {
#pragma unroll
                    for (int qt = 0; qt < 4; qt++) {
                        const int gq = qbase + qt * 16 + col;
#pragma unroll
                        for (int r = 0; r < 4; r++) {
                            const int gk = kbase + kg * 16 + quad * 4 + r;
                            st[qt][r] = (gk > gq) ? -1e30f : st[qt][r];
                        }
                    }
                }

                // p = exp2(s) raw; accumulate per-lane partial l (reduce once
                // at the end); write P half-tile (b64, packed)
#pragma unroll
                for (int qt = 0; qt < 4; qt++) {
                    bf16x4 pk;
#pragma unroll
                    for (int r = 0; r < 4; r++) {
                        float p;
                        asm("v_exp_f32 %0, %1" : "=v"(p) : "v"(st[qt][r]));
                        li[qt] += p;
                        pk[r] = (bf16)p;
                    }
                    *(bf16x4*)&plds[wv][(qt * 16 + col) * 40 + kg2 * 16 + quad * 4] = pk;
                }
            }

            __builtin_amdgcn_wave_barrier();   // P writes before P reads

            // PV for this 32-key half: O^T[d][q] += V^T[d][key] * P^T[key][q]
            bf16x8 pb[4];
#pragma unroll
            for (int qt = 0; qt < 4; qt++)
                pb[qt] = *(const bf16x8*)&plds[wv][(qt * 16 + col) * 40 + quad * 8];

            __builtin_amdgcn_s_setprio(1);
#pragma unroll
            for (int dg = 0; dg < 4; dg++) {
                bf16x8 va = *(const bf16x8*)&Vs[(dg * 16 + col) * 72 + half * 32 + quad * 8];
#pragma unroll
                for (int qt = 0; qt < 4; qt++)
                    o[dg][qt] = __builtin_amdgcn_mfma_f32_16x16x32_bf16(va, pb[qt], o[dg][qt], 0, 0, 0);
            }
            __builtin_amdgcn_s_setprio(0);
        }
    }

    // Cross-quad l reduction (keys split across quads), once per kernel
#pragma unroll
    for (int qt = 0; qt < 4; qt++) {
        li[qt] += __shfl_xor(li[qt], 16);
        li[qt] += __shfl_xor(li[qt], 32);
    }

    // Epilogue: store UNNORMALIZED partial o (bf16) + partial l (fp32).
    bf16*  Pz = z ? P1g : P0g;
    float* lz = z ? l1g : l0g;
#pragma unroll
    for (int dg = 0; dg < 4; dg++)
#pragma unroll
    for (int qt = 0; qt < 4; qt++) {
        const int gq = qbase + qt * 16 + col;
        bf16x4 ov;
#pragma unroll
        for (int r = 0; r < 4; r++) ov[r] = (bf16)o[dg][qt][r];
        *(bf16x4*)&Pz[(size_t)gq * DM + h * 64 + dg * 16 + quad * 4] = ov;
    }
    if (quad == 0) {
#pragma unroll
        for (int qt = 0; qt < 4; qt++)
            lz[(size_t)h * S + qbase + qt * 16 + col] = li[qt];
    }
}

// ---------------------------------------------------------------------------
// Combine split-K partials: ao[s][dm] = (P0 + P1) / (l0[h][s] + l1[h][s]).
// ---------------------------------------------------------------------------
__global__ __launch_bounds__(256)
void combine_kernel(const bf16* __restrict__ P0, const bf16* __restrict__ P1,
                    const float* __restrict__ l0, const float* __restrict__ l1,
                    bf16* __restrict__ ao)
{
    const size_t i    = (size_t)blockIdx.x * 256 + threadIdx.x;  // 8-elem group
    const size_t base = i * 8;
    const int s  = (int)(base >> 10);          // DM = 1024
    const int dm = (int)(base & 1023);
    const int h  = dm >> 6;
    const float rli = 1.f / (l0[(size_t)h * S + s] + l1[(size_t)h * S + s]);
    bf16x8 a = *(const bf16x8*)&P0[base];
    bf16x8 b = *(const bf16x8*)&P1[base];
    bf16x8 ov;
    for (int r = 0; r < 8; r++)
        ov[r] = (bf16)(((float)a[r] + (float)b[r]) * rli);
    *(bf16x8*)&ao[base] = ov;
}

// ---------------------------------------------------------------------------
extern "C" void kernel_launch(void* const* d_in, const int* in_sizes, int n_in,
                              void* d_out, int out_size, void* d_ws, size_t ws_size,
                              hipStream_t stream)
{
    const float* x   = (const float*)d_in[0];
    const int*   pos = (const int*)d_in[1];
    const float* Wq  = (const float*)d_in[2];
    const float* Wk  = (const float*)d_in[3];
    const float* Wv  = (const float*)d_in[4];
    const float* Wo  = (const float*)d_in[5];
    float* out = (float*)d_out;   // reference output dtype is float32

    // workspace layout (48 MB), regions recycled across phases:
    //   [0, 8M)    xb  bf16 [s][DM]        -> P0 bf16 partial (after QKV gemm)
    //   [8,16M)    wqb/wkb/wvb             -> P1 bf16 partial (after QKV gemm)
    //   [16,24M)   qb  bf16 [h][s][d]      -> ao bf16 [s][DM] (after attn)
    //   [24,32M)   kb  bf16 [h][s][d]
    //   [32,40M)   vt  bf16 [h][d][s]
    //   [40,40.25M) l0 fp32 [h][s]   [40.25,40.5M) l1 fp32 [h][s]
    //   [46,48M)   wob bf16  (must survive until out-proj -> own slot)
    char* w = (char*)d_ws;
    bf16*  xb  = (bf16*)(w);
    bf16*  wqb = (bf16*)(w + (size_t) 8 * 1024 * 1024);
    bf16*  wkb = (bf16*)(w + (size_t)10 * 1024 * 1024);
    bf16*  wvb = (bf16*)(w + (size_t)12 * 1024 * 1024);
    bf16*  P0  = (bf16*)(w);
    bf16*  P1  = (bf16*)(w + (size_t) 8 * 1024 * 1024);
    bf16*  qb  = (bf16*)(w + (size_t)16 * 1024 * 1024);
    bf16*  kb  = (bf16*)(w + (size_t)24 * 1024 * 1024);
    bf16*  vt  = (bf16*)(w + (size_t)32 * 1024 * 1024);
    float* l0  = (float*)(w + (size_t)40 * 1024 * 1024);
    float* l1  = (float*)(w + (size_t)40 * 1024 * 1024 + 256 * 1024);
    bf16*  ao  = (bf16*)(w + (size_t)16 * 1024 * 1024);   // alias qb (dead)
    bf16*  wob = (bf16*)(w + (size_t)46 * 1024 * 1024);

    dim3 blk(256);
    convert_kernel<<<dim3(8192), blk, 0, stream>>>(x, Wq, Wk, Wv, Wo,
                                                   xb, wqb, wkb, wvb, wob);
    gemm_kernel<<<dim3(32, 16, 3), blk, 0, stream>>>(xb, wqb, wkb, wvb, pos,
                                                     qb, kb, vt, out, 0);
    attn_kernel<<<dim3(512), blk, 0, stream>>>(qb, kb, vt,
                                               P0, P1, l0, l1);
    combine_kernel<<<dim3(2048), blk, 0, stream>>>(P0, P1, l0, l1, ao);
    gemm_kernel<<<dim3(32, 16, 1), blk, 0, stream>>>(ao, wob, wob, wob, pos,
                                                     qb, kb, vt, out, 3);
}